// Round 6
// baseline (275.698 us; speedup 1.0000x reference)
//
#include <hip/hip_runtime.h>
#include <stdint.h>

typedef unsigned int uint;
typedef unsigned short ushort;
typedef __attribute__((ext_vector_type(8))) short short8;
typedef __attribute__((ext_vector_type(16))) float floatx16;

#define MEG (1024u * 1024u)

// ---------- helpers ----------
__device__ inline ushort f2b(float f) {           // fp32 -> bf16 RNE
  union { float f; uint u; } c; c.f = f;
  uint u = c.u;
  u = (u + 0x7fffu + ((u >> 16) & 1u)) >> 16;
  return (ushort)u;
}
__device__ inline float b2f(ushort u) {
  union { uint i; float f; } c; c.i = ((uint)u) << 16; return c.f;
}

__device__ inline void gl_lds16(const ushort* g, ushort* l) {
  // async global->LDS, 16B/lane; LDS dest = wave-uniform base + lane*16
  __builtin_amdgcn_global_load_lds(
      (const __attribute__((address_space(1))) void*)g,
      (__attribute__((address_space(3))) void*)l, 16, 0, 0);
}

// ---------------------------------------------------------------------------
// fp32->bf16 convert (x: 4096 blocks, W: 3x512 blocks).
// ---------------------------------------------------------------------------
__global__ __launch_bounds__(256) void cvt_all(
    const float* __restrict__ x,  const float* __restrict__ wq,
    const float* __restrict__ wk, const float* __restrict__ wv,
    ushort* __restrict__ xb, ushort* __restrict__ wb)
{
  const int b = blockIdx.x;
  const float* s; ushort* d; int i;
  if (b < 4096) {
    s = x; d = xb; i = b * 256 + threadIdx.x;
  } else {
    int t = b - 4096;
    int wsel = t >> 9;
    s = (wsel == 0) ? wq : (wsel == 1) ? wk : wv;
    d = wb + (size_t)wsel * MEG;
    i = (t & 511) * 256 + threadIdx.x;
  }
  float4 a = ((const float4*)s)[i * 2];
  float4 c = ((const float4*)s)[i * 2 + 1];
  short8 v;
  v[0] = (short)f2b(a.x); v[1] = (short)f2b(a.y);
  v[2] = (short)f2b(a.z); v[3] = (short)f2b(a.w);
  v[4] = (short)f2b(c.x); v[5] = (short)f2b(c.y);
  v[6] = (short)f2b(c.z); v[7] = (short)f2b(c.w);
  ((short8*)d)[i] = v;
}

// ---------------------------------------------------------------------------
// Shared GEMM-BT core:  C[m][n] = f( sum_k A[m][k] * B[n][k] )
// 128 x BN block tile, 256 thr = 2x2 waves, MFMA 32x32x16 (floatx16 acc).
// R17 = R16 schedule (BK=32 double-buffer, ONE barrier/tile, stage-issue at
// tile TOP, 4 blocks/CU) + CORRECT pair-stripe swizzle.
//   R16's 2-bit chunk XOR on 64B rows was provably 4-way bank-conflicted
//   (6.29M conflicts measured): consecutive 8 lanes covered only 4 of 8
//   16B positions. Fix: pair rows into 128B stripes, swizzle over 8
//   positions with row parity folded in:
//     stripe q = r>>1, pos p = ((r&1)<<2 | c) ^ (q&7), byte = q*128 + p*16
//   Consecutive 8 lanes (rows r..r+7, fixed chunk c) hit positions
//   {c,c^4,c^1,c^5,c^2,c^6,c^3,c^7} = all 8 distinct = all 32 banks once
//   per group -> 0 conflicts (same property as the R5-proven BK=64 key).
//   Staging keeps gl_lds dest LINEAR (rule 21); each lane's GLOBAL source
//   is the inverse map: granule g -> q=g>>3, pp=(g&7)^(q&7),
//   r=2q+(pp>>2), c=pp&3. Round-trip verified algebraically.
//   Schedule rationale (R16): drain at tile end waits on loads issued one
//   full tile earlier (hidden under compute) AND 4 blocks/CU TLP remains.
// MODE 0 (BN=128): fused-QKV split (n<2048 -> Q/K bf16 row-major, else Vt^T)
// MODE 1 (BN=128): p = exp2(s*scale) bf16 out; per-block partial row sums
//                  plain-stored to Lp[(nb*2+nw)][bz][2048]  (R14: no atomics;
//                  |s|*scale bounded ~8 so no max subtraction, fp32-safe)
// MODE 2 (BN=128): fp32 out * 1/rowsum; rowsum = sum of 32 Lp partials
//                  (cooperative prologue into LDS Linv[128])
// ---------------------------------------------------------------------------
template <int MODE, int BN>
__device__ __forceinline__ void gemm_core(
    const ushort* __restrict__ A, int lda, size_t sA,
    const ushort* __restrict__ B, int ldb, size_t sB,
    void* __restrict__ C, int ldc, size_t sC,
    int K, float scale, float* __restrict__ Lsum)
{
  constexpr int NJ = BN / 64;          // n-frags per wave (2)
  constexpr int BI = BN / 64;          // B stage issues per tile (2)
  constexpr int ASLOT = 128 * 32;      // ushorts per A slot (8 KiB)
  constexpr int BSLOT = BN * 32;
  __shared__ ushort As[2 * ASLOT];     // 16 KiB
  __shared__ ushort Bs[2 * BSLOT];     // 16 KiB
  __shared__ float Linv[(MODE == 2) ? 128 : 1];

  const int tid = threadIdx.x;
  const int bz  = blockIdx.z;
  A += (size_t)bz * sA;
  B += (size_t)bz * sB;

  const int m0 = blockIdx.y * 128;
  const int n0 = blockIdx.x * BN;

  const int lane = tid & 63;
  const int w    = tid >> 6;
  const int l32  = lane & 31;
  const int lh   = lane >> 5;          // 0/1 -> k-half of the 16-k step
  const int mw   = w >> 1;
  const int nw   = w & 1;

  // ---- PV prologue: reduce 32 Lp partials per row -> Linv (R14) ----
  if constexpr (MODE == 2) {
    if (tid < 128) {
      float s = 0.f;
#pragma unroll
      for (int p = 0; p < 32; ++p)
        s += Lsum[((size_t)p * gridDim.z + bz) * 2048 + m0 + tid];
      Linv[tid] = 1.0f / s;
    }
    // prologue __syncthreads publishes Linv before any use
  }

  // ---- staging pointers: inverse pair-stripe swizzle on GLOBAL source ----
  // granule g = (issue*4 + w)*64 + lane; LDS byte = g*16 (linear dest).
  const ushort* agp[2];
  const ushort* bgp[BI];
#pragma unroll
  for (int q = 0; q < 2; ++q) {
    int g  = (q * 4 + w) * 64 + lane;
    int qs = g >> 3;
    int pp = (g & 7) ^ (qs & 7);
    int r  = 2 * qs + (pp >> 2);
    agp[q] = A + (size_t)(m0 + r) * lda + (pp & 3) * 8;
  }
#pragma unroll
  for (int q = 0; q < BI; ++q) {
    int g  = (q * 4 + w) * 64 + lane;
    int qs = g >> 3;
    int pp = (g & 7) ^ (qs & 7);
    int r  = 2 * qs + (pp >> 2);
    bgp[q] = B + (size_t)(n0 + r) * ldb + (pp & 3) * 8;
  }

  // ---- fragment stripe offsets + swizzle keys (loop-invariant) ----
  // read (row r, chunk cc): ushort off = (r>>1)*64 + ((cc ^ key)*8),
  // key = ((r&1)<<2) ^ ((r>>1)&7)
  int aoff[2], akey[2], boff[NJ], bkey[NJ];
#pragma unroll
  for (int t = 0; t < 2; ++t) {
    int r = mw * 64 + t * 32 + l32;
    aoff[t] = (r >> 1) * 64;
    akey[t] = ((r & 1) << 2) ^ ((r >> 1) & 7);
  }
#pragma unroll
  for (int t = 0; t < NJ; ++t) {
    int r = nw * (BN / 2) + t * 32 + l32;
    boff[t] = (r >> 1) * 64;
    bkey[t] = ((r & 1) << 2) ^ ((r >> 1) & 7);
  }

  floatx16 acc[2][NJ];
#pragma unroll
  for (int i = 0; i < 2; ++i)
#pragma unroll
    for (int j = 0; j < NJ; ++j)
#pragma unroll
      for (int r = 0; r < 16; ++r) acc[i][j][r] = 0.f;

  const int nt = K / 32;

#define STAGE(slot)                                                       \
  {                                                                       \
    ushort* Ad = &As[(slot) * ASLOT];                                     \
    ushort* Bd = &Bs[(slot) * BSLOT];                                     \
    _Pragma("unroll")                                                     \
    for (int q = 0; q < 2; ++q) {                                         \
      gl_lds16(agp[q], Ad + (q * 64 + w * 16) * 32); agp[q] += 32;        \
    }                                                                     \
    _Pragma("unroll")                                                     \
    for (int q = 0; q < BI; ++q) {                                        \
      gl_lds16(bgp[q], Bd + (q * 64 + w * 16) * 32); bgp[q] += 32;        \
    }                                                                     \
  }

  // prologue: stage tile 0; the syncthreads drain makes it resident
  STAGE(0);
  __syncthreads();

  for (int t = 0; t < nt; ++t) {
    const ushort* At = &As[(t & 1) * ASLOT];
    const ushort* Bt = &Bs[(t & 1) * BSLOT];
    if (t + 1 < nt) STAGE((t + 1) & 1);   // issue EARLY: the drain at tile
                                          // end waits on tile-old loads
#pragma unroll
    for (int s = 0; s < 2; ++s) {         // 2 k-steps of 16
      short8 af[2], bf[NJ];
#pragma unroll
      for (int i = 0; i < 2; ++i)
        af[i] = *(const short8*)&At[aoff[i] + (((s * 2 + lh) ^ akey[i]) * 8)];
#pragma unroll
      for (int j = 0; j < NJ; ++j)
        bf[j] = *(const short8*)&Bt[boff[j] + (((s * 2 + lh) ^ bkey[j]) * 8)];
#pragma unroll
      for (int i = 0; i < 2; ++i)
#pragma unroll
        for (int j = 0; j < NJ; ++j)
          acc[i][j] = __builtin_amdgcn_mfma_f32_32x32x16_bf16(
              af[i], bf[j], acc[i][j], 0, 0, 0);
    }
    __syncthreads();   // vmcnt(0)+lgkmcnt(0)+barrier: tile t+1 ready, slot
                       // t&1 free for overwrite next iteration
  }
#undef STAGE

  // ---- epilogue; C/D (32x32): col = lane&31, row = (reg&3)+8*(reg>>2)+4*lh
  if constexpr (MODE == 0) {   // fused-QKV split
#pragma unroll
    for (int i = 0; i < 2; ++i)
#pragma unroll
      for (int j = 0; j < NJ; ++j) {
        const int mbase = m0 + mw * 64 + i * 32 + 4 * lh;
        const int ng    = n0 + nw * (BN / 2) + j * 32 + l32;
        if (ng < 2048) {
          // Qb @ C, Kb @ C + 8M elems
          ushort* dst = (ushort*)C + (size_t)(ng >> 10) * (8u * MEG);
          const int nn = ng & 1023;
#pragma unroll
          for (int g = 0; g < 4; ++g)
#pragma unroll
            for (int r = 0; r < 4; ++r)
              dst[(size_t)(mbase + 8 * g + r) * 1024 + nn] =
                  f2b(acc[i][j][4 * g + r]);
        } else {
          // Vt @ C + 16M elems, transposed [1024][8192]
          ushort* Vo = (ushort*)C + (size_t)16 * MEG;
#pragma unroll
          for (int g = 0; g < 4; ++g) {
            uint lo = (uint)f2b(acc[i][j][4 * g + 0]) |
                      ((uint)f2b(acc[i][j][4 * g + 1]) << 16);
            uint hi = (uint)f2b(acc[i][j][4 * g + 2]) |
                      ((uint)f2b(acc[i][j][4 * g + 3]) << 16);
            *(uint2*)&Vo[(size_t)(ng - 2048) * 8192 + mbase + 8 * g] =
                make_uint2(lo, hi);
          }
        }
      }
  } else if constexpr (MODE == 1) {   // p = exp2(s*scale), partials -> Lp
    ushort* Cb = (ushort*)C + (size_t)bz * sC;
    float* Lp = Lsum + ((size_t)(blockIdx.x * 2 + nw) * gridDim.z + bz) * 2048;
    const int ng0 = n0 + nw * (BN / 2) + l32;
#pragma unroll
    for (int i = 0; i < 2; ++i) {
      const int mbase = m0 + mw * 64 + i * 32 + 4 * lh;
#pragma unroll
      for (int g = 0; g < 4; ++g)
#pragma unroll
        for (int r = 0; r < 4; ++r) {
          const int mg = mbase + 8 * g + r;
          float p0 = exp2f(acc[i][0][4 * g + r] * scale);
          float p1 = exp2f(acc[i][NJ - 1][4 * g + r] * scale);
          ushort u0 = f2b(p0), u1 = f2b(p1);
          Cb[(size_t)mg * ldc + ng0]      = u0;
          Cb[(size_t)mg * ldc + ng0 + 32] = u1;
          float ps = b2f(u0) + b2f(u1);   // sum of *rounded* p (matches PV)
#pragma unroll
          for (int d = 1; d < 32; d <<= 1) ps += __shfl_xor(ps, d);
          if (l32 == 0) Lp[mg] = ps;      // plain store: (nb,nw) unique slot
        }
    }
  } else {                    // MODE 2: normalized fp32 output
    float* Cb = (float*)C + (size_t)bz * sC;
#pragma unroll
    for (int i = 0; i < 2; ++i) {
      const int mbase = m0 + mw * 64 + i * 32 + 4 * lh;
#pragma unroll
      for (int g = 0; g < 4; ++g)
#pragma unroll
        for (int r = 0; r < 4; ++r) {
          const int mg = mbase + 8 * g + r;
          const float inv = Linv[mg - m0];
#pragma unroll
          for (int j = 0; j < NJ; ++j) {
            const int ng = n0 + nw * (BN / 2) + j * 32 + l32;
            Cb[(size_t)mg * ldc + ng] = acc[i][j][4 * g + r] * inv;
          }
        }
    }
  }
}

// ---- distinct symbols per stage (counter attribution) ----
// (256,4): 64 VGPR + 64 AGPR = 128 unified = the 16-wave/CU boundary (m69);
// LDS 32KB/block -> 4 blocks/CU preserved under the double-buffer.
__global__ __launch_bounds__(256, 4) void gemm_qkv(
    const ushort* __restrict__ A, int lda, size_t sA,
    const ushort* __restrict__ B, int ldb, size_t sB,
    void* __restrict__ C, int ldc, size_t sC, int K, float scale,
    float* __restrict__ Lsum) {
  gemm_core<0, 128>(A, lda, sA, B, ldb, sB, C, ldc, sC, K, scale, Lsum);
}
// S grid is exactly 1024 blocks = 4/CU x 256 CU -> one resident round.
__global__ __launch_bounds__(256, 4) void gemm_s(
    const ushort* __restrict__ A, int lda, size_t sA,
    const ushort* __restrict__ B, int ldb, size_t sB,
    void* __restrict__ C, int ldc, size_t sC, int K, float scale,
    float* __restrict__ Lsum) {
  gemm_core<1, 128>(A, lda, sA, B, ldb, sB, C, ldc, sC, K, scale, Lsum);
}
// PV BN=128 (BN=64 regressed, R15). 512 blocks = 2/CU; the issue-early
// schedule gives PV intra-block latency hiding its low block count lacks.
__global__ __launch_bounds__(256, 4) void gemm_pv(
    const ushort* __restrict__ A, int lda, size_t sA,
    const ushort* __restrict__ B, int ldb, size_t sB,
    void* __restrict__ C, int ldc, size_t sC, int K, float scale,
    float* __restrict__ Lsum) {
  gemm_core<2, 128>(A, lda, sA, B, ldb, sB, C, ldc, sC, K, scale, Lsum);
}

// ---------------------------------------------------------------------------
// ws layout (ushort elems), total 81 MiB  (proven ws >= 90.2 MB):
//   Qb @ 0      [8192][1024]   (16 MiB)
//   Kb @ 8M     [8192][1024]   (16 MiB)
//   Vt @ 16M    [1024][8192]   (16 MiB)
//   xb @ 24M    [8192][1024]   (16 MiB)  -- dead after QKV
//   Wb @ 32M    [3072][1024]   ( 6 MiB)  -- dead after QKV
//   P  @ 24M    [4][2048][2048] (32 MiB) -- OVERLAYS xb+Wb (both dead)
//   Lp @ 40M    fp32 [32][4][2048] ( 1 MiB)  -- per-(nb,nw) partial row sums
// ---------------------------------------------------------------------------
extern "C" void kernel_launch(void* const* d_in, const int* in_sizes, int n_in,
                              void* d_out, int out_size, void* d_ws, size_t ws_size,
                              hipStream_t stream) {
  const float* x  = (const float*)d_in[0];
  const float* Wq = (const float*)d_in[1];
  const float* Wk = (const float*)d_in[2];
  const float* Wv = (const float*)d_in[3];
  float* outp = (float*)d_out;

  const float SCALE = 1.4426950408889634f / 32.0f;   // log2(e)/sqrt(1024)

  ushort* W0 = (ushort*)d_ws;
  ushort* Qb = W0;
  ushort* Kb = W0 + (size_t)8 * MEG;
  ushort* Vt = W0 + (size_t)16 * MEG;
  ushort* xb = W0 + (size_t)24 * MEG;
  ushort* Wb = W0 + (size_t)32 * MEG;
  ushort* Pb = W0 + (size_t)24 * MEG;            // overlays xb/Wb after QKV

  // full: P[4] (32 MiB) + Lp 32*4*2048*4B (1 MiB)
  const size_t NEED_FULL = ((size_t)40 * MEG) * 2 + (size_t)32 * 4 * 2048 * 4;
  const bool full = ws_size >= NEED_FULL;
  float* Lp = full ? (float*)(W0 + (size_t)40 * MEG)
                   : (float*)(W0 + (size_t)28 * MEG);  // per-batch: P is 8 MiB

  cvt_all<<<5632, 256, 0, stream>>>(x, Wq, Wk, Wv, xb, Wb);

  // fused QKV projection: [8192x1024] x [3072x1024]^T, split epilogue
  gemm_qkv<<<dim3(24, 64, 1), 256, 0, stream>>>(
      xb, 1024, 0, Wb, 1024, 0, Qb, 1024, 0, 1024, 1.f, nullptr);

  if (full) {
    gemm_s<<<dim3(16, 16, 4), 256, 0, stream>>>(
        Qb, 1024, (size_t)2048 * 1024, Kb, 1024, (size_t)2048 * 1024,
        Pb, 2048, (size_t)2048 * 2048, 1024, SCALE, Lp);
    gemm_pv<<<dim3(8, 16, 4), 256, 0, stream>>>(
        Pb, 2048, (size_t)2048 * 2048, Vt, 8192, 2048,
        outp, 1024, (size_t)2048 * 1024, 2048, 1.f, Lp);
  } else {
    // per-batch fallback (P single batch @24M, Lp @28M; no memset needed —
    // every Lp slot is plain-stored exactly once per S launch)
    for (int b = 0; b < 4; ++b) {
      gemm_s<<<dim3(16, 16, 1), 256, 0, stream>>>(
          Qb + (size_t)b * 2048 * 1024, 1024, 0,
          Kb + (size_t)b * 2048 * 1024, 1024, 0,
          Pb, 2048, 0, 1024, SCALE, Lp);
      gemm_pv<<<dim3(8, 16, 1), 256, 0, stream>>>(
          Pb, 2048, 0, Vt + (size_t)b * 2048, 8192, 0,
          outp + (size_t)b * 2048 * 1024, 1024, 0, 2048, 1.f, Lp);
    }
  }
}

// Round 7
// 257.147 us; speedup vs baseline: 1.0721x; 1.0721x over previous
//
#include <hip/hip_runtime.h>
#include <stdint.h>

typedef unsigned int uint;
typedef unsigned short ushort;
typedef __attribute__((ext_vector_type(8))) short short8;
typedef __attribute__((ext_vector_type(16))) float floatx16;

#define MEG (1024u * 1024u)

// ---------- helpers ----------
__device__ inline ushort f2b(float f) {           // fp32 -> bf16 RNE
  union { float f; uint u; } c; c.f = f;
  uint u = c.u;
  u = (u + 0x7fffu + ((u >> 16) & 1u)) >> 16;
  return (ushort)u;
}
__device__ inline float b2f(ushort u) {
  union { uint i; float f; } c; c.i = ((uint)u) << 16; return c.f;
}

__device__ inline void gl_lds16(const ushort* g, ushort* l) {
  // async global->LDS, 16B/lane; LDS dest = wave-uniform base + lane*16
  __builtin_amdgcn_global_load_lds(
      (const __attribute__((address_space(1))) void*)g,
      (__attribute__((address_space(3))) void*)l, 16, 0, 0);
}

// ---------------------------------------------------------------------------
// fp32->bf16 convert (x: 4096 blocks, W: 3x512 blocks).
// ---------------------------------------------------------------------------
__global__ __launch_bounds__(256) void cvt_all(
    const float* __restrict__ x,  const float* __restrict__ wq,
    const float* __restrict__ wk, const float* __restrict__ wv,
    ushort* __restrict__ xb, ushort* __restrict__ wb)
{
  const int b = blockIdx.x;
  const float* s; ushort* d; int i;
  if (b < 4096) {
    s = x; d = xb; i = b * 256 + threadIdx.x;
  } else {
    int t = b - 4096;
    int wsel = t >> 9;
    s = (wsel == 0) ? wq : (wsel == 1) ? wk : wv;
    d = wb + (size_t)wsel * MEG;
    i = (t & 511) * 256 + threadIdx.x;
  }
  float4 a = ((const float4*)s)[i * 2];
  float4 c = ((const float4*)s)[i * 2 + 1];
  short8 v;
  v[0] = (short)f2b(a.x); v[1] = (short)f2b(a.y);
  v[2] = (short)f2b(a.z); v[3] = (short)f2b(a.w);
  v[4] = (short)f2b(c.x); v[5] = (short)f2b(c.y);
  v[6] = (short)f2b(c.z); v[7] = (short)f2b(c.w);
  ((short8*)d)[i] = v;
}

// ---------------------------------------------------------------------------
// Shared GEMM-BT core:  C[m][n] = f( sum_k A[m][k] * B[n][k] )
// 128 x BN tile, 256 thr = 2x2 waves, MFMA 32x32x16, R3's proven 2-barrier
// loop {sync; STAGE; sync; compute} — R12/R13/R16/R17 restructures all
// regressed; this structure at >=4 blocks/CU is the verified local optimum.
// R18: BK is now a template param.
//   BK=64  (QKV, S): EXACTLY the R3 kernel (0 conflicts, QKV 70.6us).
//   BK=128 (PV only): 256B rows, 16 chunks; one row per 128B+ stripe — the
//     proven-conflict-free layout family. (Both BK=32 pair-stripe variants
//     measured exactly +4 cyc/ds_read regardless of swizzle key — that
//     sub-128B-row family is empirically cursed; avoided.) PV is capped at
//     2 blocks/CU by its 512-block grid anyway, so 64KB LDS costs nothing
//     (m132's occupancy-loss mechanism doesn't apply), and halving the
//     K-tile count 32->16 halves the per-tile vmcnt(0)+barrier drains that
//     PV's low TLP can't hide.
// Swizzle (generic): row r, 16B-chunk c; stored chunk = (c&~7)|((c&7)^key),
// key = (r^(r>>3))&7 — 8 consecutive rows hit 8 distinct bank-sets.
// Pre-applied on the GLOBAL source (gl_lds dest linear, rule 21), undone on
// ds_read. No XCD swizzle (R6 regressed). BN=64 regressed (R15).
// MODE 0: fused-QKV split (n<2048 -> Q/K bf16 row-major, else Vt^T)
// MODE 1: p = exp2(s*scale) bf16 out; per-block partial row sums
//         plain-stored to Lp[(nb*2+nw)][bz][2048]  (R14: no atomics;
//         |s|*scale bounded ~8 so no max subtraction, fp32-safe)
// MODE 2: fp32 out * 1/rowsum; rowsum = sum of 32 Lp partials
//         (cooperative prologue into LDS Linv[128])
// ---------------------------------------------------------------------------
template <int MODE, int BN, int BK>
__device__ __forceinline__ void gemm_core(
    const ushort* __restrict__ A, int lda, size_t sA,
    const ushort* __restrict__ B, int ldb, size_t sB,
    void* __restrict__ C, int ldc, size_t sC,
    int K, float scale, float* __restrict__ Lsum)
{
  constexpr int NJ  = BN / 64;         // n-frags per wave (2)
  constexpr int CH  = BK / 8;          // 16B chunks per row (8 or 16)
  constexpr int KS  = BK / 16;         // k-steps per tile (4 or 8)
  constexpr int AI  = (128 * CH) / 256;  // A stage issues (4 or 8)
  constexpr int BI  = (BN * CH) / 256;   // B stage issues
  constexpr int RPI = 256 / CH;        // rows per stage issue (32 or 16)
  __shared__ ushort As[128 * BK];
  __shared__ ushort Bs[BN * BK];
  __shared__ float Linv[(MODE == 2) ? 128 : 1];

  const int tid = threadIdx.x;
  const int bz  = blockIdx.z;
  A += (size_t)bz * sA;
  B += (size_t)bz * sB;

  const int m0 = blockIdx.y * 128;
  const int n0 = blockIdx.x * BN;

  const int lane = tid & 63;
  const int w    = tid >> 6;
  const int l32  = lane & 31;
  const int lh   = lane >> 5;          // 0/1 -> k-half of the 16-k step
  const int mw   = w >> 1;
  const int nw   = w & 1;

  // ---- PV prologue: reduce 32 Lp partials per row -> Linv (R14) ----
  if constexpr (MODE == 2) {
    if (tid < 128) {
      float s = 0.f;
#pragma unroll
      for (int p = 0; p < 32; ++p)
        s += Lsum[((size_t)p * gridDim.z + bz) * 2048 + m0 + tid];
      Linv[tid] = 1.0f / s;
    }
    // first __syncthreads of the K-loop publishes Linv before any use
  }

  // ---- staging pointers: inverse swizzle on the GLOBAL source ----
  // issue q covers granules q*256+tid; row = q*RPI + tid/CH, chunk c=tid%CH;
  // stored content = global chunk (c&~7)|((c&7)^key(row)).
  const ushort* agp[AI];
  const ushort* bgp[BI];
#pragma unroll
  for (int q = 0; q < AI; ++q) {
    int r   = q * RPI + tid / CH;
    int c   = tid % CH;
    int key = (r ^ (r >> 3)) & 7;
    int sc  = (c & ~7) | ((c & 7) ^ key);
    agp[q] = A + (size_t)(m0 + r) * lda + sc * 8;
  }
#pragma unroll
  for (int q = 0; q < BI; ++q) {
    int r   = q * RPI + tid / CH;
    int c   = tid % CH;
    int key = (r ^ (r >> 3)) & 7;
    int sc  = (c & ~7) | ((c & 7) ^ key);
    bgp[q] = B + (size_t)(n0 + r) * ldb + sc * 8;
  }

  // ---- fragment rows + swizzle keys (loop-invariant) ----
  int aoff[2], akey[2], boff[NJ], bkey[NJ];
#pragma unroll
  for (int t = 0; t < 2; ++t) {
    int r = mw * 64 + t * 32 + l32;
    aoff[t] = r * BK;
    akey[t] = (r ^ (r >> 3)) & 7;
  }
#pragma unroll
  for (int t = 0; t < NJ; ++t) {
    int r = nw * (BN / 2) + t * 32 + l32;
    boff[t] = r * BK;
    bkey[t] = (r ^ (r >> 3)) & 7;
  }

  floatx16 acc[2][NJ];
#pragma unroll
  for (int i = 0; i < 2; ++i)
#pragma unroll
    for (int j = 0; j < NJ; ++j)
#pragma unroll
      for (int r = 0; r < 16; ++r) acc[i][j][r] = 0.f;

  for (int k0 = 0; k0 < K; k0 += BK) {
    __syncthreads();
#pragma unroll
    for (int q = 0; q < AI; ++q) {
      gl_lds16(agp[q], &As[(q * 256 + w * 64) * 8]);
      agp[q] += BK;
    }
#pragma unroll
    for (int q = 0; q < BI; ++q) {
      gl_lds16(bgp[q], &Bs[(q * 256 + w * 64) * 8]);
      bgp[q] += BK;
    }
    __syncthreads();

#pragma unroll
    for (int s = 0; s < KS; ++s) {       // k-steps of 16
      short8 af[2], bf[NJ];
#pragma unroll
      for (int t = 0; t < 2; ++t) {
        int cc = s * 2 + lh;
        int p  = (cc & 8) | ((cc & 7) ^ akey[t]);
        af[t] = *(const short8*)&As[aoff[t] + p * 8];
      }
#pragma unroll
      for (int t = 0; t < NJ; ++t) {
        int cc = s * 2 + lh;
        int p  = (cc & 8) | ((cc & 7) ^ bkey[t]);
        bf[t] = *(const short8*)&Bs[boff[t] + p * 8];
      }
#pragma unroll
      for (int i = 0; i < 2; ++i)
#pragma unroll
        for (int j = 0; j < NJ; ++j)
          acc[i][j] = __builtin_amdgcn_mfma_f32_32x32x16_bf16(
              af[i], bf[j], acc[i][j], 0, 0, 0);
    }
  }

  // ---- epilogue; C/D (32x32): col = lane&31, row = (reg&3)+8*(reg>>2)+4*lh
  if constexpr (MODE == 0) {   // fused-QKV split
#pragma unroll
    for (int i = 0; i < 2; ++i)
#pragma unroll
      for (int j = 0; j < NJ; ++j) {
        const int mbase = m0 + mw * 64 + i * 32 + 4 * lh;
        const int ng    = n0 + nw * (BN / 2) + j * 32 + l32;
        if (ng < 2048) {
          // Qb @ C, Kb @ C + 8M elems
          ushort* dst = (ushort*)C + (size_t)(ng >> 10) * (8u * MEG);
          const int nn = ng & 1023;
#pragma unroll
          for (int g = 0; g < 4; ++g)
#pragma unroll
            for (int r = 0; r < 4; ++r)
              dst[(size_t)(mbase + 8 * g + r) * 1024 + nn] =
                  f2b(acc[i][j][4 * g + r]);
        } else {
          // Vt @ C + 16M elems, transposed [1024][8192]
          ushort* Vo = (ushort*)C + (size_t)16 * MEG;
#pragma unroll
          for (int g = 0; g < 4; ++g) {
            uint lo = (uint)f2b(acc[i][j][4 * g + 0]) |
                      ((uint)f2b(acc[i][j][4 * g + 1]) << 16);
            uint hi = (uint)f2b(acc[i][j][4 * g + 2]) |
                      ((uint)f2b(acc[i][j][4 * g + 3]) << 16);
            *(uint2*)&Vo[(size_t)(ng - 2048) * 8192 + mbase + 8 * g] =
                make_uint2(lo, hi);
          }
        }
      }
  } else if constexpr (MODE == 1) {   // p = exp2(s*scale), partials -> Lp
    ushort* Cb = (ushort*)C + (size_t)bz * sC;
    float* Lp = Lsum + ((size_t)(blockIdx.x * 2 + nw) * gridDim.z + bz) * 2048;
    const int ng0 = n0 + nw * (BN / 2) + l32;
#pragma unroll
    for (int i = 0; i < 2; ++i) {
      const int mbase = m0 + mw * 64 + i * 32 + 4 * lh;
#pragma unroll
      for (int g = 0; g < 4; ++g)
#pragma unroll
        for (int r = 0; r < 4; ++r) {
          const int mg = mbase + 8 * g + r;
          float p0 = exp2f(acc[i][0][4 * g + r] * scale);
          float p1 = exp2f(acc[i][NJ - 1][4 * g + r] * scale);
          ushort u0 = f2b(p0), u1 = f2b(p1);
          Cb[(size_t)mg * ldc + ng0]      = u0;
          Cb[(size_t)mg * ldc + ng0 + 32] = u1;
          float ps = b2f(u0) + b2f(u1);   // sum of *rounded* p (matches PV)
#pragma unroll
          for (int d = 1; d < 32; d <<= 1) ps += __shfl_xor(ps, d);
          if (l32 == 0) Lp[mg] = ps;      // plain store: (nb,nw) unique slot
        }
    }
  } else {                    // MODE 2: normalized fp32 output
    float* Cb = (float*)C + (size_t)bz * sC;
#pragma unroll
    for (int i = 0; i < 2; ++i) {
      const int mbase = m0 + mw * 64 + i * 32 + 4 * lh;
#pragma unroll
      for (int g = 0; g < 4; ++g)
#pragma unroll
        for (int r = 0; r < 4; ++r) {
          const int mg = mbase + 8 * g + r;
          const float inv = Linv[mg - m0];
#pragma unroll
          for (int j = 0; j < NJ; ++j) {
            const int ng = n0 + nw * (BN / 2) + j * 32 + l32;
            Cb[(size_t)mg * ldc + ng] = acc[i][j][4 * g + r] * inv;
          }
        }
    }
  }
}

// ---- distinct symbols per stage (counter attribution) ----
// (256,4): 64 VGPR + 64 AGPR = 128 unified = the 16-wave/CU boundary (m69);
// LDS 32KB/block -> 4 blocks/CU.
__global__ __launch_bounds__(256, 4) void gemm_qkv(
    const ushort* __restrict__ A, int lda, size_t sA,
    const ushort* __restrict__ B, int ldb, size_t sB,
    void* __restrict__ C, int ldc, size_t sC, int K, float scale,
    float* __restrict__ Lsum) {
  gemm_core<0, 128, 64>(A, lda, sA, B, ldb, sB, C, ldc, sC, K, scale, Lsum);
}
// S grid is exactly 1024 blocks = 4/CU x 256 CU -> one resident round.
__global__ __launch_bounds__(256, 4) void gemm_s(
    const ushort* __restrict__ A, int lda, size_t sA,
    const ushort* __restrict__ B, int ldb, size_t sB,
    void* __restrict__ C, int ldc, size_t sC, int K, float scale,
    float* __restrict__ Lsum) {
  gemm_core<1, 128, 64>(A, lda, sA, B, ldb, sB, C, ldc, sC, K, scale, Lsum);
}
// R18: PV BK=128. 512 blocks are capped at 2 blocks/CU regardless, so the
// 64KB LDS is free; K-tiles 32->16 halves the per-tile drain count that
// PV's low TLP can't hide. (256,2) caps regs at 256/wave (needs ~160).
__global__ __launch_bounds__(256, 2) void gemm_pv(
    const ushort* __restrict__ A, int lda, size_t sA,
    const ushort* __restrict__ B, int ldb, size_t sB,
    void* __restrict__ C, int ldc, size_t sC, int K, float scale,
    float* __restrict__ Lsum) {
  gemm_core<2, 128, 128>(A, lda, sA, B, ldb, sB, C, ldc, sC, K, scale, Lsum);
}

// ---------------------------------------------------------------------------
// ws layout (ushort elems), total 81 MiB  (proven ws >= 90.2 MB):
//   Qb @ 0      [8192][1024]   (16 MiB)
//   Kb @ 8M     [8192][1024]   (16 MiB)
//   Vt @ 16M    [1024][8192]   (16 MiB)
//   xb @ 24M    [8192][1024]   (16 MiB)  -- dead after QKV
//   Wb @ 32M    [3072][1024]   ( 6 MiB)  -- dead after QKV
//   P  @ 24M    [4][2048][2048] (32 MiB) -- OVERLAYS xb+Wb (both dead)
//   Lp @ 40M    fp32 [32][4][2048] ( 1 MiB)  -- per-(nb,nw) partial row sums
// ---------------------------------------------------------------------------
extern "C" void kernel_launch(void* const* d_in, const int* in_sizes, int n_in,
                              void* d_out, int out_size, void* d_ws, size_t ws_size,
                              hipStream_t stream) {
  const float* x  = (const float*)d_in[0];
  const float* Wq = (const float*)d_in[1];
  const float* Wk = (const float*)d_in[2];
  const float* Wv = (const float*)d_in[3];
  float* outp = (float*)d_out;

  const float SCALE = 1.4426950408889634f / 32.0f;   // log2(e)/sqrt(1024)

  ushort* W0 = (ushort*)d_ws;
  ushort* Qb = W0;
  ushort* Kb = W0 + (size_t)8 * MEG;
  ushort* Vt = W0 + (size_t)16 * MEG;
  ushort* xb = W0 + (size_t)24 * MEG;
  ushort* Wb = W0 + (size_t)32 * MEG;
  ushort* Pb = W0 + (size_t)24 * MEG;            // overlays xb/Wb after QKV

  // full: P[4] (32 MiB) + Lp 32*4*2048*4B (1 MiB)
  const size_t NEED_FULL = ((size_t)40 * MEG) * 2 + (size_t)32 * 4 * 2048 * 4;
  const bool full = ws_size >= NEED_FULL;
  float* Lp = full ? (float*)(W0 + (size_t)40 * MEG)
                   : (float*)(W0 + (size_t)28 * MEG);  // per-batch: P is 8 MiB

  cvt_all<<<5632, 256, 0, stream>>>(x, Wq, Wk, Wv, xb, Wb);

  // fused QKV projection: [8192x1024] x [3072x1024]^T, split epilogue
  gemm_qkv<<<dim3(24, 64, 1), 256, 0, stream>>>(
      xb, 1024, 0, Wb, 1024, 0, Qb, 1024, 0, 1024, 1.f, nullptr);

  if (full) {
    gemm_s<<<dim3(16, 16, 4), 256, 0, stream>>>(
        Qb, 1024, (size_t)2048 * 1024, Kb, 1024, (size_t)2048 * 1024,
        Pb, 2048, (size_t)2048 * 2048, 1024, SCALE, Lp);
    gemm_pv<<<dim3(8, 16, 4), 256, 0, stream>>>(
        Pb, 2048, (size_t)2048 * 2048, Vt, 8192, 2048,
        outp, 1024, (size_t)2048 * 1024, 2048, 1.f, Lp);
  } else {
    // per-batch fallback (P single batch @24M, Lp @28M; no memset needed —
    // every Lp slot is plain-stored exactly once per S launch)
    for (int b = 0; b < 4; ++b) {
      gemm_s<<<dim3(16, 16, 1), 256, 0, stream>>>(
          Qb + (size_t)b * 2048 * 1024, 1024, 0,
          Kb + (size_t)b * 2048 * 1024, 1024, 0,
          Pb, 2048, 0, 1024, SCALE, Lp);
      gemm_pv<<<dim3(8, 16, 1), 256, 0, stream>>>(
          Pb, 2048, 0, Vt + (size_t)b * 2048, 8192, 0,
          outp + (size_t)b * 2048 * 1024, 1024, 0, 2048, 1.f, Lp);
    }
  }
}

// Round 8
// 252.831 us; speedup vs baseline: 1.0904x; 1.0171x over previous
//
#include <hip/hip_runtime.h>
#include <stdint.h>

typedef unsigned int uint;
typedef unsigned short ushort;
typedef __attribute__((ext_vector_type(8))) short short8;
typedef __attribute__((ext_vector_type(16))) float floatx16;

#define MEG (1024u * 1024u)

// ---------- helpers ----------
__device__ inline ushort f2b(float f) {           // fp32 -> bf16 RNE
  union { float f; uint u; } c; c.f = f;
  uint u = c.u;
  u = (u + 0x7fffu + ((u >> 16) & 1u)) >> 16;
  return (ushort)u;
}
__device__ inline float b2f(ushort u) {
  union { uint i; float f; } c; c.i = ((uint)u) << 16; return c.f;
}

__device__ inline void gl_lds16(const ushort* g, ushort* l) {
  // async global->LDS, 16B/lane; LDS dest = wave-uniform base + lane*16
  __builtin_amdgcn_global_load_lds(
      (const __attribute__((address_space(1))) void*)g,
      (__attribute__((address_space(3))) void*)l, 16, 0, 0);
}

// ---------------------------------------------------------------------------
// fp32->bf16 convert (x: 4096 blocks, W: 3x512 blocks).
// ---------------------------------------------------------------------------
__global__ __launch_bounds__(256) void cvt_all(
    const float* __restrict__ x,  const float* __restrict__ wq,
    const float* __restrict__ wk, const float* __restrict__ wv,
    ushort* __restrict__ xb, ushort* __restrict__ wb)
{
  const int b = blockIdx.x;
  const float* s; ushort* d; int i;
  if (b < 4096) {
    s = x; d = xb; i = b * 256 + threadIdx.x;
  } else {
    int t = b - 4096;
    int wsel = t >> 9;
    s = (wsel == 0) ? wq : (wsel == 1) ? wk : wv;
    d = wb + (size_t)wsel * MEG;
    i = (t & 511) * 256 + threadIdx.x;
  }
  float4 a = ((const float4*)s)[i * 2];
  float4 c = ((const float4*)s)[i * 2 + 1];
  short8 v;
  v[0] = (short)f2b(a.x); v[1] = (short)f2b(a.y);
  v[2] = (short)f2b(a.z); v[3] = (short)f2b(a.w);
  v[4] = (short)f2b(c.x); v[5] = (short)f2b(c.y);
  v[6] = (short)f2b(c.z); v[7] = (short)f2b(c.w);
  ((short8*)d)[i] = v;
}

// ---------------------------------------------------------------------------
// R3-proven GEMM-BT core (QKV, S):  C[m][n] = f( sum_k A[m][k] * B[n][k] )
// 128 x 128 tile, BK=64, 256 thr = 2x2 waves, MFMA 32x32x16, 2-barrier loop
// {sync; STAGE; sync; compute} at 4 blocks/CU. XOR-swizzled [rows][64] LDS
// (chunk' = chunk ^ ((r^(r>>3))&7)): 0 bank conflicts measured.
// Negative results (do not retry): 256^2 single-block schedules (R12/R13),
// BK=32 any swizzle (exactly +4cyc/ds_read: sub-128B-row family cursed),
// PV BN=64 (R15), PV BK=128 (R18), XCD swizzle (R6).
// MODE 0: fused-QKV split (n<2048 -> Q/K bf16 row-major, else Vt^T)
// MODE 1: p = exp2(s*scale) bf16 out; per-block partial row sums
//         plain-stored to Lp[(nb*2+nw)][bz][2048]  (no atomics; |s|*scale
//         bounded ~8 so no max subtraction needed, fp32-safe)
// ---------------------------------------------------------------------------
template <int MODE, int BN>
__device__ __forceinline__ void gemm_core(
    const ushort* __restrict__ A, int lda, size_t sA,
    const ushort* __restrict__ B, int ldb, size_t sB,
    void* __restrict__ C, int ldc, size_t sC,
    int K, float scale, float* __restrict__ Lsum)
{
  constexpr int NJ = BN / 64;          // n-frags per wave (2)
  constexpr int NB = BN / 32;          // 32-row staging groups for B (4)
  __shared__ ushort As[128 * 64];
  __shared__ ushort Bs[BN * 64];

  const int tid = threadIdx.x;
  const int bz  = blockIdx.z;
  A += (size_t)bz * sA;
  B += (size_t)bz * sB;

  const int m0 = blockIdx.y * 128;
  const int n0 = blockIdx.x * BN;

  const int lane = tid & 63;
  const int w    = tid >> 6;
  const int l32  = lane & 31;
  const int lh   = lane >> 5;          // 0/1 -> k-half of the 16-k step
  const int mw   = w >> 1;
  const int nw   = w & 1;

  // ---- staging pointers (32 rows per group; 8 lanes per 128B row) ----
  const int srow = tid >> 3;
  const ushort* agp[4];
  const ushort* bgp[NB];
#pragma unroll
  for (int c4 = 0; c4 < 4; ++c4) {
    int r   = c4 * 32 + srow;
    int col = (((tid & 7) ^ ((r ^ (r >> 3)) & 7))) * 8;
    agp[c4] = A + (size_t)(m0 + r) * lda + col;
  }
#pragma unroll
  for (int cb = 0; cb < NB; ++cb) {
    int r   = cb * 32 + srow;
    int col = (((tid & 7) ^ ((r ^ (r >> 3)) & 7))) * 8;
    bgp[cb] = B + (size_t)(n0 + r) * ldb + col;
  }

  // ---- fragment rows + swizzle keys (loop-invariant) ----
  int arow[2], aswz[2], brow[NJ], bswz[NJ];
#pragma unroll
  for (int t = 0; t < 2; ++t) {
    arow[t] = mw * 64 + t * 32 + l32;
    aswz[t] = (arow[t] ^ (arow[t] >> 3)) & 7;
  }
#pragma unroll
  for (int t = 0; t < NJ; ++t) {
    brow[t] = nw * (BN / 2) + t * 32 + l32;
    bswz[t] = (brow[t] ^ (brow[t] >> 3)) & 7;
  }

  floatx16 acc[2][NJ];
#pragma unroll
  for (int i = 0; i < 2; ++i)
#pragma unroll
    for (int j = 0; j < NJ; ++j)
#pragma unroll
      for (int r = 0; r < 16; ++r) acc[i][j][r] = 0.f;

  for (int k0 = 0; k0 < K; k0 += 64) {
    __syncthreads();
#pragma unroll
    for (int c4 = 0; c4 < 4; ++c4) {
      gl_lds16(agp[c4], &As[(c4 * 32 + w * 8) * 64]);
      agp[c4] += 64;
    }
#pragma unroll
    for (int cb = 0; cb < NB; ++cb) {
      gl_lds16(bgp[cb], &Bs[(cb * 32 + w * 8) * 64]);
      bgp[cb] += 64;
    }
    __syncthreads();

#pragma unroll
    for (int s = 0; s < 4; ++s) {        // 4 k-steps of 16
      short8 af[2], bf[NJ];
#pragma unroll
      for (int t = 0; t < 2; ++t)
        af[t] = *(const short8*)&As[arow[t] * 64 + (((s * 2 + lh) ^ aswz[t]) * 8)];
#pragma unroll
      for (int t = 0; t < NJ; ++t)
        bf[t] = *(const short8*)&Bs[brow[t] * 64 + (((s * 2 + lh) ^ bswz[t]) * 8)];
#pragma unroll
      for (int i = 0; i < 2; ++i)
#pragma unroll
        for (int j = 0; j < NJ; ++j)
          acc[i][j] = __builtin_amdgcn_mfma_f32_32x32x16_bf16(
              af[i], bf[j], acc[i][j], 0, 0, 0);
    }
  }

  // ---- epilogue; C/D (32x32): col = lane&31, row = (reg&3)+8*(reg>>2)+4*lh
  if constexpr (MODE == 0) {   // fused-QKV split
#pragma unroll
    for (int i = 0; i < 2; ++i)
#pragma unroll
      for (int j = 0; j < NJ; ++j) {
        const int mbase = m0 + mw * 64 + i * 32 + 4 * lh;
        const int ng    = n0 + nw * (BN / 2) + j * 32 + l32;
        if (ng < 2048) {
          // Qb @ C, Kb @ C + 8M elems
          ushort* dst = (ushort*)C + (size_t)(ng >> 10) * (8u * MEG);
          const int nn = ng & 1023;
#pragma unroll
          for (int g = 0; g < 4; ++g)
#pragma unroll
            for (int r = 0; r < 4; ++r)
              dst[(size_t)(mbase + 8 * g + r) * 1024 + nn] =
                  f2b(acc[i][j][4 * g + r]);
        } else {
          // Vt @ C + 16M elems, transposed [1024][8192]
          ushort* Vo = (ushort*)C + (size_t)16 * MEG;
#pragma unroll
          for (int g = 0; g < 4; ++g) {
            uint lo = (uint)f2b(acc[i][j][4 * g + 0]) |
                      ((uint)f2b(acc[i][j][4 * g + 1]) << 16);
            uint hi = (uint)f2b(acc[i][j][4 * g + 2]) |
                      ((uint)f2b(acc[i][j][4 * g + 3]) << 16);
            *(uint2*)&Vo[(size_t)(ng - 2048) * 8192 + mbase + 8 * g] =
                make_uint2(lo, hi);
          }
        }
      }
  } else {                            // MODE 1: p = exp2, partials -> Lp
    ushort* Cb = (ushort*)C + (size_t)bz * sC;
    float* Lp = Lsum + ((size_t)(blockIdx.x * 2 + nw) * gridDim.z + bz) * 2048;
    const int ng0 = n0 + nw * (BN / 2) + l32;
#pragma unroll
    for (int i = 0; i < 2; ++i) {
      const int mbase = m0 + mw * 64 + i * 32 + 4 * lh;
#pragma unroll
      for (int g = 0; g < 4; ++g)
#pragma unroll
        for (int r = 0; r < 4; ++r) {
          const int mg = mbase + 8 * g + r;
          float p0 = exp2f(acc[i][0][4 * g + r] * scale);
          float p1 = exp2f(acc[i][NJ - 1][4 * g + r] * scale);
          ushort u0 = f2b(p0), u1 = f2b(p1);
          Cb[(size_t)mg * ldc + ng0]      = u0;
          Cb[(size_t)mg * ldc + ng0 + 32] = u1;
          float ps = b2f(u0) + b2f(u1);   // sum of *rounded* p (matches PV)
#pragma unroll
          for (int d = 1; d < 32; d <<= 1) ps += __shfl_xor(ps, d);
          if (l32 == 0) Lp[mg] = ps;      // plain store: (nb,nw) unique slot
        }
    }
  }
}

// ---- distinct symbols per stage (counter attribution) ----
// (256,4): 64 VGPR + 64 AGPR = 128 unified = the 16-wave/CU boundary (m69);
// LDS 32KB/block -> 4 blocks/CU.
__global__ __launch_bounds__(256, 4) void gemm_qkv(
    const ushort* __restrict__ A, int lda, size_t sA,
    const ushort* __restrict__ B, int ldb, size_t sB,
    void* __restrict__ C, int ldc, size_t sC, int K, float scale,
    float* __restrict__ Lsum) {
  gemm_core<0, 128>(A, lda, sA, B, ldb, sB, C, ldc, sC, K, scale, Lsum);
}
// S grid is exactly 1024 blocks = 4/CU x 256 CU -> one resident round.
__global__ __launch_bounds__(256, 4) void gemm_s(
    const ushort* __restrict__ A, int lda, size_t sA,
    const ushort* __restrict__ B, int ldb, size_t sB,
    void* __restrict__ C, int ldc, size_t sC, int K, float scale,
    float* __restrict__ Lsum) {
  gemm_core<1, 128>(A, lda, sA, B, ldb, sB, C, ldc, sC, K, scale, Lsum);
}

// ---------------------------------------------------------------------------
// R19: PV-only issue-early double-buffer. PV is capped at 2 blocks/CU by its
// 512-block grid, so a 2-slot BK=64 buffer (64KB LDS) is occupancy-FREE —
// unlike QKV/S where it would halve residency. Schedule: stage tile t+1 at
// the TOP of tile t, ONE __syncthreads per tile — the implicit vmcnt(0)
// drain waits on loads issued a full compute phase earlier instead of 0
// cycles earlier. This targets exactly the deficit PV's 2-way TLP can't
// hide (R3's adjacent issue->drain relies on >=4 blocks/CU of overlap).
// LDS layout/swizzle INSIDE each slot is byte-identical to the 0-conflict
// R3 layout. Race-freedom: slot s^1 staged during tile t was last read in
// tile t-1 (lgkm-drained at t-1's end barrier: WAW safe); tile t reads
// slot s staged at top of t-1, drained at t-1's end barrier (RAW safe).
// MODE 2 epilogue: fp32 out * 1/rowsum; rowsum = sum of 32 Lp partials
// (cooperative prologue into LDS Linv[128], published by prologue barrier).
// ---------------------------------------------------------------------------
__global__ __launch_bounds__(256, 2) void gemm_pv(
    const ushort* __restrict__ A, int lda, size_t sA,
    const ushort* __restrict__ B, int ldb, size_t sB,
    void* __restrict__ C, int ldc, size_t sC, int K, float scale,
    float* __restrict__ Lsum)
{
  constexpr int SLOT = 128 * 64;       // ushorts per slot (16 KiB)
  __shared__ ushort As[2 * SLOT];      // 32 KiB
  __shared__ ushort Bs[2 * SLOT];      // 32 KiB
  __shared__ float Linv[128];

  const int tid = threadIdx.x;
  const int bz  = blockIdx.z;
  A += (size_t)bz * sA;
  B += (size_t)bz * sB;

  const int m0 = blockIdx.y * 128;
  const int n0 = blockIdx.x * 128;

  const int lane = tid & 63;
  const int w    = tid >> 6;
  const int l32  = lane & 31;
  const int lh   = lane >> 5;
  const int mw   = w >> 1;
  const int nw   = w & 1;

  // ---- prologue: reduce 32 Lp partials per row -> Linv ----
  if (tid < 128) {
    float s = 0.f;
#pragma unroll
    for (int p = 0; p < 32; ++p)
      s += Lsum[((size_t)p * gridDim.z + bz) * 2048 + m0 + tid];
    Linv[tid] = 1.0f / s;
  }

  // ---- staging pointers (32 rows per group; 8 lanes per 128B row) ----
  const int srow = tid >> 3;
  const ushort* agp[4];
  const ushort* bgp[4];
#pragma unroll
  for (int c4 = 0; c4 < 4; ++c4) {
    int r   = c4 * 32 + srow;
    int col = (((tid & 7) ^ ((r ^ (r >> 3)) & 7))) * 8;
    agp[c4] = A + (size_t)(m0 + r) * lda + col;
    bgp[c4] = B + (size_t)(n0 + r) * ldb + col;
  }

  // ---- fragment rows + swizzle keys ----
  int arow[2], aswz[2], brow[2], bswz[2];
#pragma unroll
  for (int t = 0; t < 2; ++t) {
    arow[t] = mw * 64 + t * 32 + l32;
    aswz[t] = (arow[t] ^ (arow[t] >> 3)) & 7;
    brow[t] = nw * 64 + t * 32 + l32;
    bswz[t] = (brow[t] ^ (brow[t] >> 3)) & 7;
  }

  floatx16 acc[2][2];
#pragma unroll
  for (int i = 0; i < 2; ++i)
#pragma unroll
    for (int j = 0; j < 2; ++j)
#pragma unroll
      for (int r = 0; r < 16; ++r) acc[i][j][r] = 0.f;

  const int nt = K / 64;

#define PV_STAGE(slot)                                                    \
  {                                                                       \
    ushort* Ad = &As[(slot) * SLOT];                                      \
    ushort* Bd = &Bs[(slot) * SLOT];                                      \
    _Pragma("unroll")                                                     \
    for (int c4 = 0; c4 < 4; ++c4) {                                      \
      gl_lds16(agp[c4], Ad + (c4 * 32 + w * 8) * 64); agp[c4] += 64;      \
      gl_lds16(bgp[c4], Bd + (c4 * 32 + w * 8) * 64); bgp[c4] += 64;      \
    }                                                                     \
  }

  PV_STAGE(0);
  __syncthreads();          // publishes Linv AND makes tile 0 resident

  for (int t = 0; t < nt; ++t) {
    const ushort* At = &As[(t & 1) * SLOT];
    const ushort* Bt = &Bs[(t & 1) * SLOT];
    if (t + 1 < nt) PV_STAGE((t + 1) & 1);   // issue EARLY

#pragma unroll
    for (int s = 0; s < 4; ++s) {
      short8 af[2], bf[2];
#pragma unroll
      for (int i = 0; i < 2; ++i)
        af[i] = *(const short8*)&At[arow[i] * 64 + (((s * 2 + lh) ^ aswz[i]) * 8)];
#pragma unroll
      for (int j = 0; j < 2; ++j)
        bf[j] = *(const short8*)&Bt[brow[j] * 64 + (((s * 2 + lh) ^ bswz[j]) * 8)];
#pragma unroll
      for (int i = 0; i < 2; ++i)
#pragma unroll
        for (int j = 0; j < 2; ++j)
          acc[i][j] = __builtin_amdgcn_mfma_f32_32x32x16_bf16(
              af[i], bf[j], acc[i][j], 0, 0, 0);
    }
    __syncthreads();        // drain: waits on loads issued one tile ago
  }
#undef PV_STAGE

  // ---- epilogue: normalized fp32 output ----
  float* Cb = (float*)C + (size_t)bz * sC;
#pragma unroll
  for (int i = 0; i < 2; ++i) {
    const int mbase = m0 + mw * 64 + i * 32 + 4 * lh;
#pragma unroll
    for (int g = 0; g < 4; ++g)
#pragma unroll
      for (int r = 0; r < 4; ++r) {
        const int mg = mbase + 8 * g + r;
        const float inv = Linv[mg - m0];
#pragma unroll
        for (int j = 0; j < 2; ++j) {
          const int ng = n0 + nw * 64 + j * 32 + l32;
          Cb[(size_t)mg * ldc + ng] = acc[i][j][4 * g + r] * inv;
        }
      }
  }
}

// ---------------------------------------------------------------------------
// ws layout (ushort elems), total 81 MiB  (proven ws >= 90.2 MB):
//   Qb @ 0      [8192][1024]   (16 MiB)
//   Kb @ 8M     [8192][1024]   (16 MiB)
//   Vt @ 16M    [1024][8192]   (16 MiB)
//   xb @ 24M    [8192][1024]   (16 MiB)  -- dead after QKV
//   Wb @ 32M    [3072][1024]   ( 6 MiB)  -- dead after QKV
//   P  @ 24M    [4][2048][2048] (32 MiB) -- OVERLAYS xb+Wb (both dead)
//   Lp @ 40M    fp32 [32][4][2048] ( 1 MiB)  -- per-(nb,nw) partial row sums
// ---------------------------------------------------------------------------
extern "C" void kernel_launch(void* const* d_in, const int* in_sizes, int n_in,
                              void* d_out, int out_size, void* d_ws, size_t ws_size,
                              hipStream_t stream) {
  const float* x  = (const float*)d_in[0];
  const float* Wq = (const float*)d_in[1];
  const float* Wk = (const float*)d_in[2];
  const float* Wv = (const float*)d_in[3];
  float* outp = (float*)d_out;

  const float SCALE = 1.4426950408889634f / 32.0f;   // log2(e)/sqrt(1024)

  ushort* W0 = (ushort*)d_ws;
  ushort* Qb = W0;
  ushort* Kb = W0 + (size_t)8 * MEG;
  ushort* Vt = W0 + (size_t)16 * MEG;
  ushort* xb = W0 + (size_t)24 * MEG;
  ushort* Wb = W0 + (size_t)32 * MEG;
  ushort* Pb = W0 + (size_t)24 * MEG;            // overlays xb/Wb after QKV

  // full: P[4] (32 MiB) + Lp 32*4*2048*4B (1 MiB)
  const size_t NEED_FULL = ((size_t)40 * MEG) * 2 + (size_t)32 * 4 * 2048 * 4;
  const bool full = ws_size >= NEED_FULL;
  float* Lp = full ? (float*)(W0 + (size_t)40 * MEG)
                   : (float*)(W0 + (size_t)28 * MEG);  // per-batch: P is 8 MiB

  cvt_all<<<5632, 256, 0, stream>>>(x, Wq, Wk, Wv, xb, Wb);

  // fused QKV projection: [8192x1024] x [3072x1024]^T, split epilogue
  gemm_qkv<<<dim3(24, 64, 1), 256, 0, stream>>>(
      xb, 1024, 0, Wb, 1024, 0, Qb, 1024, 0, 1024, 1.f, nullptr);

  if (full) {
    gemm_s<<<dim3(16, 16, 4), 256, 0, stream>>>(
        Qb, 1024, (size_t)2048 * 1024, Kb, 1024, (size_t)2048 * 1024,
        Pb, 2048, (size_t)2048 * 2048, 1024, SCALE, Lp);
    gemm_pv<<<dim3(8, 16, 4), 256, 0, stream>>>(
        Pb, 2048, (size_t)2048 * 2048, Vt, 8192, 2048,
        outp, 1024, (size_t)2048 * 1024, 2048, 1.f, Lp);
  } else {
    // per-batch fallback (P single batch @24M, Lp @28M; no memset needed —
    // every Lp slot is plain-stored exactly once per S launch)
    for (int b = 0; b < 4; ++b) {
      gemm_s<<<dim3(16, 16, 1), 256, 0, stream>>>(
          Qb + (size_t)b * 2048 * 1024, 1024, 0,
          Kb + (size_t)b * 2048 * 1024, 1024, 0,
          Pb, 2048, 0, 1024, SCALE, Lp);
      gemm_pv<<<dim3(8, 16, 1), 256, 0, stream>>>(
          Pb, 2048, 0, Vt + (size_t)b * 2048, 8192, 0,
          outp + (size_t)b * 2048 * 1024, 1024, 0, 2048, 1.f, Lp);
    }
  }
}